// Round 2
// baseline (664.110 us; speedup 1.0000x reference)
//
#include <hip/hip_runtime.h>

#define DIM1 512
#define DIM2 128

typedef __bf16 bf16_t;
typedef bf16_t bf16x8 __attribute__((ext_vector_type(8)));
typedef bf16_t bf16x4 __attribute__((ext_vector_type(4)));
typedef float  f32x16 __attribute__((ext_vector_type(16)));

// ---------- prep: X fp32 [4096][512] -> Xp bf16 [js=64][n=4096][8] (A-frag layout)
//                                      + XT bf16 [i=512][n=4096]    (epilogue layout)
__global__ __launch_bounds__(256)
void prep_kernel(const float* __restrict__ X, bf16_t* __restrict__ Xp, bf16_t* __restrict__ XT)
{
    const int bn = blockIdx.x & 63;   // n-tile (64 rows)
    const int bi = blockIdx.x >> 6;   // j/i-tile (64 cols)
    const int t  = threadIdx.x;
    __shared__ float tile[64][65];

    {
        const int r  = t >> 2;
        const int c0 = (t & 3) * 16;
        const float* src = X + (size_t)(bn * 64 + r) * DIM1 + bi * 64 + c0;
        #pragma unroll
        for (int q = 0; q < 4; ++q) {
            float4 v = *reinterpret_cast<const float4*>(src + q * 4);
            tile[r][c0 + q * 4 + 0] = v.x;
            tile[r][c0 + q * 4 + 1] = v.y;
            tile[r][c0 + q * 4 + 2] = v.z;
            tile[r][c0 + q * 4 + 3] = v.w;
        }
    }
    __syncthreads();

    // Xp[js][n][e], js = j/8: coalesced 16B stores, contiguous in n
    #pragma unroll
    for (int p = 0; p < 2; ++p) {
        const int nl = (t & 31) + p * 32;
        const int jg = t >> 5;                 // 0..7
        bf16x8 h;
        #pragma unroll
        for (int e = 0; e < 8; ++e) h[e] = (bf16_t)tile[nl][jg * 8 + e];
        *reinterpret_cast<bf16x8*>(Xp + ((size_t)(bi * 8 + jg) * 4096 + bn * 64 + nl) * 8) = h;
    }
    // XT[i][n]: transpose via LDS, coalesced stores
    #pragma unroll
    for (int p = 0; p < 2; ++p) {
        const int il = (t >> 3) + p * 32;      // 0..63
        const int n8 = (t & 7) * 8;
        bf16x8 h;
        #pragma unroll
        for (int e = 0; e < 8; ++e) h[e] = (bf16_t)tile[n8 + e][il];
        *reinterpret_cast<bf16x8*>(XT + (size_t)(bi * 64 + il) * 4096 + bn * 64 + n8) = h;
    }
}

// ---------- main: Y[n,k] = sum_{i,j} X[n,i] W[k,i,j] X[n,j]
// Block: 512 thr (8 waves), 1 k, 512 rows. Wave: 64 rows (m=2 x 32-row frags).
// 32x32x16 MFMA: acc[n,i] partial over 128-j chunk, folded into ypart via XT.
// W tile [64 i][128 j] bf16 in LDS, paired-row + 5-bit XOR swizzle, double-buffered.
template<bool USE_WS>
__global__ __launch_bounds__(512, 2)
void tr_main(const float* __restrict__ X, const float* __restrict__ W,
             const bf16_t* __restrict__ Xp, const bf16_t* __restrict__ XT,
             float* __restrict__ Y)
{
    const int bid = blockIdx.x;
    const int kk  = (bid & 7) + 8 * (bid >> 6);   // same-k's 8 nb-blocks on one XCD
    const int nb  = ((bid >> 3) & 7) * 512;

    const int tid = threadIdx.x;
    const int w   = tid >> 6;
    const int l   = tid & 63;
    const int l31 = l & 31;
    const int lh  = l >> 5;
    const int rowbase = nb + w * 64;

    __shared__ bf16_t Wt[2][32 * 256];   // 2 x 16 KB

    const float* Wk = W + (size_t)kk * (DIM1 * DIM1);

    // staging coords: thread covers row sr, 16 floats at col sc
    const int sr  = tid >> 3;            // 0..63
    const int sc  = (tid & 7) * 16;      // 0..112
    const int spr = sr >> 1;
    const int sv  = ((sr & 1) << 8) | (sc * 2);
    const int ssw = (spr & 31) << 4;

    bf16x8 afrag[2][8];
    float  ypart[2][16];
    #pragma unroll
    for (int m = 0; m < 2; ++m)
        #pragma unroll
        for (int r = 0; r < 16; ++r) ypart[m][r] = 0.f;

    float4 st[4];

    auto load_afrag = [&](int jc) {
        #pragma unroll
        for (int m = 0; m < 2; ++m) {
            const int n = rowbase + m * 32 + l31;
            #pragma unroll
            for (int ks = 0; ks < 8; ++ks) {
                if constexpr (USE_WS) {
                    const int js = jc * 16 + ks * 2 + lh;
                    afrag[m][ks] = *reinterpret_cast<const bf16x8*>(
                        Xp + ((size_t)js * 4096 + n) * 8);
                } else {
                    const float* s = X + (size_t)n * DIM1 + jc * 128 + ks * 16 + lh * 8;
                    float4 a = *reinterpret_cast<const float4*>(s);
                    float4 b = *reinterpret_cast<const float4*>(s + 4);
                    bf16x8 h = {(bf16_t)a.x, (bf16_t)a.y, (bf16_t)a.z, (bf16_t)a.w,
                                (bf16_t)b.x, (bf16_t)b.y, (bf16_t)b.z, (bf16_t)b.w};
                    afrag[m][ks] = h;
                }
            }
        }
    };

    auto stage_load = [&](int s1) {   // issue global loads for step s1 (early)
        const int it = s1 & 7, jc = s1 >> 3;
        const float* src = Wk + (size_t)(it * 64 + sr) * DIM1 + jc * 128 + sc;
        #pragma unroll
        for (int qq = 0; qq < 4; ++qq)
            st[qq] = *reinterpret_cast<const float4*>(src + qq * 4);
    };

    auto stage_write = [&](int buf) {  // cvt + swizzled LDS write (late)
        bf16x8 h0 = {(bf16_t)st[0].x, (bf16_t)st[0].y, (bf16_t)st[0].z, (bf16_t)st[0].w,
                     (bf16_t)st[1].x, (bf16_t)st[1].y, (bf16_t)st[1].z, (bf16_t)st[1].w};
        bf16x8 h1 = {(bf16_t)st[2].x, (bf16_t)st[2].y, (bf16_t)st[2].z, (bf16_t)st[2].w,
                     (bf16_t)st[3].x, (bf16_t)st[3].y, (bf16_t)st[3].z, (bf16_t)st[3].w};
        char* base = (char*)(&Wt[buf][0]) + spr * 512;
        *reinterpret_cast<bf16x8*>(base + ((sv)      ^ ssw)) = h0;
        *reinterpret_cast<bf16x8*>(base + ((sv + 16) ^ ssw)) = h1;
    };

    load_afrag(0);
    stage_load(0);
    stage_write(0);
    __syncthreads();

    for (int s = 0; s < 32; ++s) {       // jc = s>>3 (4 x 128-j), it = s&7 (8 x 64-i)
        const int it  = s & 7;
        const int cur = s & 1;
        if (s < 31) stage_load(s + 1);

        f32x16 acc[2][2] = {};
        #pragma unroll
        for (int ks = 0; ks < 8; ++ks) {
            #pragma unroll
            for (int f = 0; f < 2; ++f) {
                const int i  = f * 32 + l31;
                const int pr = i >> 1;
                const int v  = (((i & 1) << 8) | (ks * 32 + lh * 16)) ^ ((pr & 31) << 4);
                bf16x8 b = *reinterpret_cast<const bf16x8*>(
                    (const char*)(&Wt[cur][0]) + pr * 512 + v);
                acc[0][f] = __builtin_amdgcn_mfma_f32_32x32x16_bf16(afrag[0][ks], b, acc[0][f], 0, 0, 0);
                acc[1][f] = __builtin_amdgcn_mfma_f32_32x32x16_bf16(afrag[1][ks], b, acc[1][f], 0, 0, 0);
            }
        }

        if ((s & 7) == 7 && s < 31) load_afrag((s + 1) >> 3);

        // fold partial acc into ypart: ypart[n] += acc[n,i] * X[n,i]
        // C/D: col(i)=l&31, row(n)=(reg&3)+8*(reg>>2)+4*lh
        #pragma unroll
        for (int m = 0; m < 2; ++m) {
            #pragma unroll
            for (int f = 0; f < 2; ++f) {
                const int i = it * 64 + f * 32 + l31;
                #pragma unroll
                for (int g = 0; g < 4; ++g) {
                    const int n0 = rowbase + m * 32 + g * 8 + lh * 4;
                    float x0, x1, x2, x3;
                    if constexpr (USE_WS) {
                        bf16x4 x4 = *reinterpret_cast<const bf16x4*>(XT + (size_t)i * 4096 + n0);
                        x0 = (float)x4[0]; x1 = (float)x4[1]; x2 = (float)x4[2]; x3 = (float)x4[3];
                    } else {
                        const float* xs = X + (size_t)n0 * DIM1 + i;
                        x0 = xs[0]; x1 = xs[DIM1]; x2 = xs[2 * DIM1]; x3 = xs[3 * DIM1];
                    }
                    ypart[m][g * 4 + 0] += acc[m][f][g * 4 + 0] * x0;
                    ypart[m][g * 4 + 1] += acc[m][f][g * 4 + 1] * x1;
                    ypart[m][g * 4 + 2] += acc[m][f][g * 4 + 2] * x2;
                    ypart[m][g * 4 + 3] += acc[m][f][g * 4 + 3] * x3;
                }
            }
        }

        if (s < 31) stage_write(cur ^ 1);
        __syncthreads();
    }

    // reduce over the 32 i-lanes and store
    #pragma unroll
    for (int m = 0; m < 2; ++m) {
        #pragma unroll
        for (int r = 0; r < 16; ++r) {
            float v2 = ypart[m][r];
            v2 += __shfl_xor(v2, 1);
            v2 += __shfl_xor(v2, 2);
            v2 += __shfl_xor(v2, 4);
            v2 += __shfl_xor(v2, 8);
            v2 += __shfl_xor(v2, 16);
            if (l31 == 0) {
                const int n = rowbase + m * 32 + (r & 3) + 8 * (r >> 2) + 4 * lh;
                Y[(size_t)n * DIM2 + kk] = v2;
            }
        }
    }
}

extern "C" void kernel_launch(void* const* d_in, const int* in_sizes, int n_in,
                              void* d_out, int out_size, void* d_ws, size_t ws_size,
                              hipStream_t stream)
{
    const float* X = (const float*)d_in[0];   // [4096, 512] fp32
    const float* W = (const float*)d_in[1];   // [128, 512, 512] fp32
    float* Y = (float*)d_out;                 // [4096, 128] fp32

    const bool ws_ok = (d_ws != nullptr) && (ws_size >= (size_t)8 * 1024 * 1024);
    if (ws_ok) {
        bf16_t* Xp = (bf16_t*)d_ws;                         // 4 MB
        bf16_t* XT = (bf16_t*)d_ws + (size_t)2 * 1024 * 1024; // 4 MB (element offset)
        prep_kernel<<<512, 256, 0, stream>>>(X, Xp, XT);
        tr_main<true><<<1024, 512, 0, stream>>>(X, W, Xp, XT, Y);
    } else {
        tr_main<false><<<1024, 512, 0, stream>>>(X, W, nullptr, nullptr, Y);
    }
}

// Round 3
// 404.496 us; speedup vs baseline: 1.6418x; 1.6418x over previous
//
#include <hip/hip_runtime.h>

#define D1 512
#define K2 128

typedef __bf16 bf16_t;
typedef bf16_t bf16x8 __attribute__((ext_vector_type(8)));
typedef bf16_t bf16x4 __attribute__((ext_vector_type(4)));
typedef float  f32x4  __attribute__((ext_vector_type(4)));
typedef float  f32x16 __attribute__((ext_vector_type(16)));

#define WBF_OFF 0ull
#define XBF_OFF 67108864ull
#define XT_OFF  71303168ull
#define WS_NEED 75497472ull

// ---------------- prep W: fp32 [k][i][j] -> Wbf bf16 A-frag stream ----------------
// Wbf[k][is(16)][s(32)][l(64)][e(8)]: lane l of a wave loads 16B = W[k][is*32+(l&31)][s*16+(l>>5)*8+e]
__global__ __launch_bounds__(256)
void prep_w(const float* __restrict__ W, bf16_t* __restrict__ Wbf)
{
    const int k  = blockIdx.x >> 4;
    const int is = blockIdx.x & 15;
    const int t  = threadIdx.x;
    __shared__ float lt[16384];            // 32 rows x 2048 B, 16B-slot XOR swizzle
    char* ltb = (char*)lt;
    {
        const int r  = t >> 3;
        const int cb = (t & 7) * 64;
        const float* src = W + ((size_t)k * D1 + is * 32 + r) * D1 + cb;
        const int sw = (r & 15) << 4;
        #pragma unroll
        for (int c = 0; c < 16; ++c) {
            float4 v = *reinterpret_cast<const float4*>(src + c * 4);
            *reinterpret_cast<float4*>(ltb + r * 2048 + (((cb + c * 4) * 4) ^ sw)) = v;
        }
    }
    __syncthreads();
    bf16_t* out = Wbf + ((size_t)k * 16 + is) * 16384;
    #pragma unroll
    for (int p = 0; p < 8; ++p) {
        const int cc = p * 256 + t;        // 0..2047 = s*64 + l
        const int s  = cc >> 6;
        const int l2 = cc & 63;
        const int il = l2 & 31;
        const int jb = s * 16 + (l2 >> 5) * 8;
        const int sw = (il & 15) << 4;
        bf16x8 h;
        #pragma unroll
        for (int e = 0; e < 8; ++e) {
            float v = *reinterpret_cast<const float*>(ltb + il * 2048 + (((jb + e) * 4) ^ sw));
            h[e] = (bf16_t)v;
        }
        *reinterpret_cast<bf16x8*>(out + (size_t)cc * 8) = h;
    }
}

// ---------------- prep X: fp32 [n][d] -> Xbf (B-frag LDS image, pre-swizzled) + XT bf16 [d][n]
// Xbf[nb2(32)][jc(4)][chunk(2048)][e(8)]: chunk = n*16+slot, content = X[nb2*128+n][jc*128+(slot^(n&15))*8+e]
__global__ __launch_bounds__(256)
void prep_x(const float* __restrict__ X, bf16_t* __restrict__ Xbf, bf16_t* __restrict__ XT)
{
    const int nb2 = blockIdx.x >> 2;
    const int jc  = blockIdx.x & 3;
    const int t   = threadIdx.x;
    __shared__ float xt[16384];            // [128 n][128 j]
    {
        const int nl = t >> 1;
        const int cb = (t & 1) * 64;
        const float* src = X + ((size_t)nb2 * 128 + nl) * D1 + jc * 128 + cb;
        #pragma unroll
        for (int c = 0; c < 16; ++c) {
            float4 v = *reinterpret_cast<const float4*>(src + c * 4);
            *reinterpret_cast<float4*>(&xt[nl * 128 + cb + c * 4]) = v;
        }
    }
    __syncthreads();
    bf16_t* outx = Xbf + ((size_t)nb2 * 4 + jc) * 16384;
    #pragma unroll
    for (int p = 0; p < 8; ++p) {
        const int cc   = p * 256 + t;
        const int n    = cc >> 4;
        const int slot = cc & 15;
        const int j8   = slot ^ (n & 15);
        bf16x8 h;
        #pragma unroll
        for (int e = 0; e < 8; ++e) h[e] = (bf16_t)xt[n * 128 + j8 * 8 + e];
        *reinterpret_cast<bf16x8*>(outx + (size_t)cc * 8) = h;
    }
    {
        const int jl  = t >> 1;
        const int nlb = (t & 1) * 64;
        bf16_t* dst = XT + (size_t)(jc * 128 + jl) * 4096 + nb2 * 128 + nlb;
        #pragma unroll
        for (int u8 = 0; u8 < 8; ++u8) {
            bf16x8 h;
            #pragma unroll
            for (int e = 0; e < 8; ++e) h[e] = (bf16_t)xt[(nlb + u8 * 8 + e) * 128 + jl];
            *reinterpret_cast<bf16x8*>(dst + u8 * 8) = h;
        }
    }
}

// ---------------- main: W-as-A, X-as-B. Block = (k, n-tile of 128), 8 waves.
// Wave w owns i-strip [w*64, w*64+64). acc[mi][fn] over full j=512. Epilogue once.
__global__ __launch_bounds__(512, 2)
void tr_main(const bf16_t* __restrict__ Wbf, const bf16_t* __restrict__ Xbf,
             const bf16_t* __restrict__ XT, float* __restrict__ Y)
{
    extern __shared__ char smem[];         // 4 x 32 KB X tiles + 4 KB reduce
    float* red = (float*)(smem + 131072);

    const int bid = blockIdx.x;
    const int k   = ((bid >> 8) << 3) + (bid & 7);   // same-k blocks share an XCD per round
    const int nb2 = (bid >> 3) & 31;

    const int tid = threadIdx.x;
    const int w   = tid >> 6;
    const int l   = tid & 63;
    const int l31 = l & 31;
    const int lh  = l >> 5;

    // stage all 4 X tiles (pre-swizzled image -> linear LDS), reg-staged, coalesced
    {
        const bf16_t* src = Xbf + (size_t)nb2 * 65536;
        bf16x8 tmp[16];
        #pragma unroll
        for (int jc = 0; jc < 4; ++jc)
            #pragma unroll
            for (int p = 0; p < 4; ++p) {
                const int ci = (p * 8 + w) * 64 + l;
                tmp[jc * 4 + p] = *reinterpret_cast<const bf16x8*>(
                    src + (size_t)jc * 16384 + (size_t)ci * 8);
            }
        #pragma unroll
        for (int jc = 0; jc < 4; ++jc)
            #pragma unroll
            for (int p = 0; p < 4; ++p) {
                const int ci = (p * 8 + w) * 64 + l;
                *reinterpret_cast<bf16x8*>(smem + jc * 32768 + ci * 16) = tmp[jc * 4 + p];
            }
    }
    __syncthreads();

    const bf16_t* A0 = Wbf + ((size_t)k * 16 + (w * 2 + 0)) * 16384 + (size_t)l * 8;
    const bf16_t* A1 = Wbf + ((size_t)k * 16 + (w * 2 + 1)) * 16384 + (size_t)l * 8;
    const int sw = (l & 15) << 4;

    f32x16 acc[2][4] = {};

    bf16x8 Ac[2], An[2];
    Ac[0] = *reinterpret_cast<const bf16x8*>(A0);
    Ac[1] = *reinterpret_cast<const bf16x8*>(A1);
    An[0] = *reinterpret_cast<const bf16x8*>(A0 + 512);
    An[1] = *reinterpret_cast<const bf16x8*>(A1 + 512);

    #pragma unroll
    for (int s = 0; s < 32; ++s) {         // j-step of 16; jc = s>>3 selects tile
        const int jc  = s >> 3;
        const int ks2 = s & 7;
        bf16x8 Af[2];
        if (s + 2 < 32) {
            Af[0] = *reinterpret_cast<const bf16x8*>(A0 + (size_t)(s + 2) * 512);
            Af[1] = *reinterpret_cast<const bf16x8*>(A1 + (size_t)(s + 2) * 512);
        }
        const int ct = (ks2 * 32 + lh * 16) ^ sw;
        bf16x8 bfr[4];
        #pragma unroll
        for (int fn = 0; fn < 4; ++fn)
            bfr[fn] = *reinterpret_cast<const bf16x8*>(
                smem + jc * 32768 + (fn * 32 + l31) * 256 + ct);
        #pragma unroll
        for (int mi = 0; mi < 2; ++mi)
            #pragma unroll
            for (int fn = 0; fn < 4; ++fn)
                acc[mi][fn] = __builtin_amdgcn_mfma_f32_32x32x16_bf16(
                    Ac[mi], bfr[fn], acc[mi][fn], 0, 0, 0);
        Ac[0] = An[0]; Ac[1] = An[1];
        An[0] = Af[0]; An[1] = Af[1];
    }

    // epilogue: ypart[n] = sum_i acc[i,n] * X[n,i]; col(n)=l&31, row(i)=(r&3)+8*(r>>2)+4*lh
    float yp[4] = {0.f, 0.f, 0.f, 0.f};
    #pragma unroll
    for (int mi = 0; mi < 2; ++mi) {
        const int ib = w * 64 + mi * 32 + 4 * lh;
        #pragma unroll
        for (int fn = 0; fn < 4; ++fn) {
            const size_t ncol = (size_t)nb2 * 128 + fn * 32 + l31;
            #pragma unroll
            for (int r = 0; r < 16; ++r) {
                const int i = ib + (r & 3) + 8 * (r >> 2);
                yp[fn] += acc[mi][fn][r] * (float)XT[(size_t)i * 4096 + ncol];
            }
        }
    }
    #pragma unroll
    for (int fn = 0; fn < 4; ++fn) {
        float v = yp[fn];
        v += __shfl_down(v, 32);
        if (lh == 0) red[w * 128 + fn * 32 + l31] = v;
    }
    __syncthreads();
    if (tid < 128) {
        float s2 = 0.f;
        #pragma unroll
        for (int w2 = 0; w2 < 8; ++w2) s2 += red[w2 * 128 + tid];
        Y[((size_t)nb2 * 128 + tid) * K2 + k] = s2;
    }
}

// ---------------- fallback (R1, proven 458 us, no ws) ----------------
__global__ __launch_bounds__(512, 2)
void tensor_reduction_kernel(const float* __restrict__ X,
                             const float* __restrict__ W,
                             float* __restrict__ Y)
{
    const int bid = blockIdx.x;
    const int xcd = bid & 7;
    const int rr_ = bid >> 3;
    const int kk  = xcd + 8 * (rr_ >> 4);
    const int nb  = (rr_ & 15) * 256;

    const int tid = threadIdx.x;
    const int wv  = tid >> 6;
    const int ln  = tid & 63;
    const int lg  = ln >> 4;
    const int lr  = ln & 15;

    __shared__ __align__(16) bf16_t Xs[256 * 64];
    __shared__ __align__(16) bf16_t Ws[2][64 * 64];

    bf16x8 afrag[2][16];
    {
        const int srow = tid >> 4;
        const int sj4  = (tid & 15) * 4;
        #pragma unroll
        for (int c = 0; c < 8; ++c) {
            #pragma unroll
            for (int p = 0; p < 8; ++p) {
                const int row = p * 32 + srow;
                float4 v = *reinterpret_cast<const float4*>(
                    X + (size_t)(nb + row) * D1 + c * 64 + sj4);
                bf16x4 h = { (bf16_t)v.x, (bf16_t)v.y, (bf16_t)v.z, (bf16_t)v.w };
                const int byte = row * 128 + ((sj4 * 2) ^ ((row & 7) << 4));
                *reinterpret_cast<bf16x4*>((char*)Xs + byte) = h;
            }
            __syncthreads();
            #pragma unroll
            for (int m = 0; m < 2; ++m) {
                #pragma unroll
                for (int ks = 0; ks < 2; ++ks) {
                    const int row  = wv * 32 + m * 16 + lr;
                    const int byte = row * 128 + ((ks * 64 + lg * 16) ^ ((row & 7) << 4));
                    afrag[m][2 * c + ks] =
                        *reinterpret_cast<const bf16x8*>((const char*)Xs + byte);
                }
            }
            __syncthreads();
        }
    }

    const float* Wk  = W + (size_t)kk * D1 * D1;
    const int irow = tid >> 3;
    const int j8   = (tid & 7) * 8;

    float ypart[2][4] = {{0.f,0.f,0.f,0.f},{0.f,0.f,0.f,0.f}};

    {
        const float* src = Wk + (size_t)irow * D1 + j8;
        float4 u0 = *reinterpret_cast<const float4*>(src);
        float4 u1 = *reinterpret_cast<const float4*>(src + 4);
        bf16x8 h = { (bf16_t)u0.x,(bf16_t)u0.y,(bf16_t)u0.z,(bf16_t)u0.w,
                     (bf16_t)u1.x,(bf16_t)u1.y,(bf16_t)u1.z,(bf16_t)u1.w };
        const int byte = irow * 128 + ((j8 * 2) ^ ((irow & 7) << 4));
        *reinterpret_cast<bf16x8*>((char*)Ws[0] + byte) = h;
    }
    __syncthreads();

    for (int it = 0; it < 8; ++it) {
        f32x4 acc[2][4] = {};
        #pragma unroll
        for (int jcc = 0; jcc < 8; ++jcc) {
            const int tI  = it * 8 + jcc;
            const int cur = tI & 1;
            float4 u0, u1;
            const bool pf = (tI < 63);
            if (pf) {
                const int nit = (tI + 1) >> 3, njc = (tI + 1) & 7;
                const float* src = Wk + (size_t)(nit * 64 + irow) * D1 + njc * 64 + j8;
                u0 = *reinterpret_cast<const float4*>(src);
                u1 = *reinterpret_cast<const float4*>(src + 4);
            }
            #pragma unroll
            for (int ks = 0; ks < 2; ++ks) {
                bf16x8 bfr[4];
                #pragma unroll
                for (int f = 0; f < 4; ++f) {
                    const int ir   = f * 16 + lr;
                    const int byte = ir * 128 + ((ks * 64 + lg * 16) ^ ((ir & 7) << 4));
                    bfr[f] = *reinterpret_cast<const bf16x8*>((const char*)Ws[cur] + byte);
                }
                #pragma unroll
                for (int m = 0; m < 2; ++m)
                    #pragma unroll
                    for (int f = 0; f < 4; ++f)
                        acc[m][f] = __builtin_amdgcn_mfma_f32_16x16x32_bf16(
                            afrag[m][2 * jcc + ks], bfr[f], acc[m][f], 0, 0, 0);
            }
            if (pf) {
                bf16x8 h = { (bf16_t)u0.x,(bf16_t)u0.y,(bf16_t)u0.z,(bf16_t)u0.w,
                             (bf16_t)u1.x,(bf16_t)u1.y,(bf16_t)u1.z,(bf16_t)u1.w };
                const int byte = irow * 128 + ((j8 * 2) ^ ((irow & 7) << 4));
                *reinterpret_cast<bf16x8*>((char*)Ws[cur ^ 1] + byte) = h;
            }
            __syncthreads();
        }
        #pragma unroll
        for (int m = 0; m < 2; ++m) {
            #pragma unroll
            for (int f = 0; f < 4; ++f) {
                const int col = it * 64 + f * 16 + lr;
                #pragma unroll
                for (int q = 0; q < 4; ++q) {
                    const int grow = nb + wv * 32 + m * 16 + lg * 4 + q;
                    ypart[m][q] += acc[m][f][q] * X[(size_t)grow * D1 + col];
                }
            }
        }
    }

    #pragma unroll
    for (int m = 0; m < 2; ++m) {
        #pragma unroll
        for (int q = 0; q < 4; ++q) {
            float v = ypart[m][q];
            v += __shfl_xor(v, 1, 64);
            v += __shfl_xor(v, 2, 64);
            v += __shfl_xor(v, 4, 64);
            v += __shfl_xor(v, 8, 64);
            if (lr == 0) {
                const int grow = nb + wv * 32 + m * 16 + lg * 4 + q;
                Y[(size_t)grow * K2 + kk] = v;
            }
        }
    }
}

extern "C" void kernel_launch(void* const* d_in, const int* in_sizes, int n_in,
                              void* d_out, int out_size, void* d_ws, size_t ws_size,
                              hipStream_t stream)
{
    const float* X = (const float*)d_in[0];   // [4096, 512] fp32
    const float* W = (const float*)d_in[1];   // [128, 512, 512] fp32
    float* Y = (float*)d_out;                 // [4096, 128] fp32

    if (d_ws != nullptr && ws_size >= WS_NEED) {
        bf16_t* Wbf = (bf16_t*)((char*)d_ws + WBF_OFF);
        bf16_t* Xbf = (bf16_t*)((char*)d_ws + XBF_OFF);
        bf16_t* XTp = (bf16_t*)((char*)d_ws + XT_OFF);
        prep_w<<<2048, 256, 0, stream>>>(W, Wbf);
        prep_x<<<128, 256, 0, stream>>>(X, Xbf, XTp);
        (void)hipFuncSetAttribute((const void*)tr_main,
                                  hipFuncAttributeMaxDynamicSharedMemorySize, 135168);
        tr_main<<<4096, 512, 135168, stream>>>(Wbf, Xbf, XTp, Y);
    } else {
        tensor_reduction_kernel<<<2048, 512, 0, stream>>>(X, W, Y);
    }
}

// Round 4
// 304.987 us; speedup vs baseline: 2.1775x; 1.3263x over previous
//
#include <hip/hip_runtime.h>

#define D1 512
#define K2 128

typedef __bf16 bf16_t;
typedef bf16_t bf16x8 __attribute__((ext_vector_type(8)));
typedef bf16_t bf16x4 __attribute__((ext_vector_type(4)));
typedef float  f32x4  __attribute__((ext_vector_type(4)));
typedef float  f32x16 __attribute__((ext_vector_type(16)));

#define WBF_OFF 0ull
#define XBF_OFF 67108864ull
#define WS_NEED 71303168ull

// ---------------- prep W: fp32 [k][i][j] -> Wbf bf16 A-frag stream ----------------
// Wbf[k][is(16)][s(32)][l(64)][e(8)]: lane l of a wave loads 16B = W[k][is*32+(l&31)][s*16+(l>>5)*8+e]
__global__ __launch_bounds__(256)
void prep_w(const float* __restrict__ W, bf16_t* __restrict__ Wbf)
{
    const int k  = blockIdx.x >> 4;
    const int is = blockIdx.x & 15;
    const int t  = threadIdx.x;
    __shared__ float lt[16384];            // 32 rows x 2048 B, 16B-slot XOR swizzle
    char* ltb = (char*)lt;
    {
        const int r  = t >> 3;
        const int cb = (t & 7) * 64;
        const float* src = W + ((size_t)k * D1 + is * 32 + r) * D1 + cb;
        const int sw = (r & 15) << 4;
        #pragma unroll
        for (int c = 0; c < 16; ++c) {
            float4 v = *reinterpret_cast<const float4*>(src + c * 4);
            *reinterpret_cast<float4*>(ltb + r * 2048 + (((cb + c * 4) * 4) ^ sw)) = v;
        }
    }
    __syncthreads();
    bf16_t* out = Wbf + ((size_t)k * 16 + is) * 16384;
    #pragma unroll
    for (int p = 0; p < 8; ++p) {
        const int cc = p * 256 + t;        // 0..2047 = s*64 + l
        const int s  = cc >> 6;
        const int l2 = cc & 63;
        const int il = l2 & 31;
        const int jb = s * 16 + (l2 >> 5) * 8;
        const int sw = (il & 15) << 4;
        bf16x8 h;
        #pragma unroll
        for (int e = 0; e < 8; ++e) {
            float v = *reinterpret_cast<const float*>(ltb + il * 2048 + (((jb + e) * 4) ^ sw));
            h[e] = (bf16_t)v;
        }
        *reinterpret_cast<bf16x8*>(out + (size_t)cc * 8) = h;
    }
}

// ---------------- prep X: fp32 [n][d] -> Xbf (B-frag LDS image, pre-swizzled)
// Xbf[nb2(32)][jc(4)][chunk(2048)][e(8)]: chunk = n*16+slot, content = X[nb2*128+n][jc*128+(slot^(n&15))*8+e]
__global__ __launch_bounds__(256)
void prep_x(const float* __restrict__ X, bf16_t* __restrict__ Xbf)
{
    const int nb2 = blockIdx.x >> 2;
    const int jc  = blockIdx.x & 3;
    const int t   = threadIdx.x;
    __shared__ float xt[16384];            // [128 n][128 j]
    {
        const int nl = t >> 1;
        const int cb = (t & 1) * 64;
        const float* src = X + ((size_t)nb2 * 128 + nl) * D1 + jc * 128 + cb;
        #pragma unroll
        for (int c = 0; c < 16; ++c) {
            float4 v = *reinterpret_cast<const float4*>(src + c * 4);
            *reinterpret_cast<float4*>(&xt[nl * 128 + cb + c * 4]) = v;
        }
    }
    __syncthreads();
    bf16_t* outx = Xbf + ((size_t)nb2 * 4 + jc) * 16384;
    #pragma unroll
    for (int p = 0; p < 8; ++p) {
        const int cc   = p * 256 + t;
        const int n    = cc >> 4;
        const int slot = cc & 15;
        const int j8   = slot ^ (n & 15);
        bf16x8 h;
        #pragma unroll
        for (int e = 0; e < 8; ++e) h[e] = (bf16_t)xt[n * 128 + j8 * 8 + e];
        *reinterpret_cast<bf16x8*>(outx + (size_t)cc * 8) = h;
    }
}

// ---------------- main: W-as-A, X-as-B. Block = (k, n-tile of 128), 8 waves.
// Wave w owns i-strip [w*64, w*64+64). acc[mi][fn] over full j=512.
// Epilogue folds acc[i,n]*X[n,i] with X read straight from the staged LDS tiles.
__global__ __launch_bounds__(512, 2)
void tr_main(const bf16_t* __restrict__ Wbf, const bf16_t* __restrict__ Xbf,
             float* __restrict__ Y)
{
    extern __shared__ char smem[];         // 4 x 32 KB X tiles + 4 KB reduce
    float* red = (float*)(smem + 131072);

    const int bid = blockIdx.x;
    const int k   = ((bid >> 8) << 3) + (bid & 7);   // same-k blocks share an XCD per round
    const int nb2 = (bid >> 3) & 31;

    const int tid = threadIdx.x;
    const int w   = tid >> 6;
    const int l   = tid & 63;
    const int l31 = l & 31;
    const int lh  = l >> 5;

    // stage all 4 X tiles (pre-swizzled image -> linear LDS), reg-staged, coalesced
    {
        const bf16_t* src = Xbf + (size_t)nb2 * 65536;
        bf16x8 tmp[16];
        #pragma unroll
        for (int jc = 0; jc < 4; ++jc)
            #pragma unroll
            for (int p = 0; p < 4; ++p) {
                const int ci = (p * 8 + w) * 64 + l;
                tmp[jc * 4 + p] = *reinterpret_cast<const bf16x8*>(
                    src + (size_t)jc * 16384 + (size_t)ci * 8);
            }
        #pragma unroll
        for (int jc = 0; jc < 4; ++jc)
            #pragma unroll
            for (int p = 0; p < 4; ++p) {
                const int ci = (p * 8 + w) * 64 + l;
                *reinterpret_cast<bf16x8*>(smem + jc * 32768 + ci * 16) = tmp[jc * 4 + p];
            }
    }
    __syncthreads();

    const bf16_t* A0 = Wbf + ((size_t)k * 16 + (w * 2 + 0)) * 16384 + (size_t)l * 8;
    const bf16_t* A1 = Wbf + ((size_t)k * 16 + (w * 2 + 1)) * 16384 + (size_t)l * 8;
    const int sw = (l & 15) << 4;

    f32x16 acc[2][4] = {};

    // depth-4 A-prefetch queue (statically indexed under full unroll)
    bf16x8 Aq[4][2];
    #pragma unroll
    for (int d = 0; d < 4; ++d) {
        Aq[d][0] = *reinterpret_cast<const bf16x8*>(A0 + (size_t)d * 512);
        Aq[d][1] = *reinterpret_cast<const bf16x8*>(A1 + (size_t)d * 512);
    }

    #pragma unroll
    for (int s = 0; s < 32; ++s) {         // j-step of 16; jc = s>>3 selects tile
        const int jc  = s >> 3;
        const int ks2 = s & 7;
        const int qi  = s & 3;
        bf16x8 a0 = Aq[qi][0];
        bf16x8 a1 = Aq[qi][1];
        if (s + 4 < 32) {
            Aq[qi][0] = *reinterpret_cast<const bf16x8*>(A0 + (size_t)(s + 4) * 512);
            Aq[qi][1] = *reinterpret_cast<const bf16x8*>(A1 + (size_t)(s + 4) * 512);
        }
        const int ct = (ks2 * 32 + lh * 16) ^ sw;
        bf16x8 bfr[4];
        #pragma unroll
        for (int fn = 0; fn < 4; ++fn)
            bfr[fn] = *reinterpret_cast<const bf16x8*>(
                smem + jc * 32768 + (fn * 32 + l31) * 256 + ct);
        #pragma unroll
        for (int fn = 0; fn < 4; ++fn) {
            acc[0][fn] = __builtin_amdgcn_mfma_f32_32x32x16_bf16(a0, bfr[fn], acc[0][fn], 0, 0, 0);
            acc[1][fn] = __builtin_amdgcn_mfma_f32_32x32x16_bf16(a1, bfr[fn], acc[1][fn], 0, 0, 0);
        }
    }

    // epilogue: yp[n] = sum_i acc[i,n] * X[n,i], X from staged LDS tiles.
    // C/D: col(n)=l&31, row(i)=(r&3)+8*(r>>2)+4*lh. i-quads are 4-consecutive -> ds_read_b64.
    float yp[4] = {0.f, 0.f, 0.f, 0.f};
    #pragma unroll
    for (int mi = 0; mi < 2; ++mi) {
        const int ibase = w * 64 + mi * 32;          // 32-aligned
        const int jc    = (w * 2 + mi) >> 2;         // i>>7, constant per (w,mi)
        #pragma unroll
        for (int rq = 0; rq < 4; ++rq) {
            const int slot = (((ibase >> 3) + rq) & 15);
            #pragma unroll
            for (int fn = 0; fn < 4; ++fn) {
                const int n = fn * 32 + l31;
                const char* p = smem + jc * 32768 + n * 256
                              + ((slot ^ (n & 15)) << 4) + lh * 8;
                bf16x4 xv = *reinterpret_cast<const bf16x4*>(p);
                #pragma unroll
                for (int q = 0; q < 4; ++q)
                    yp[fn] += acc[mi][fn][rq * 4 + q] * (float)xv[q];
            }
        }
    }
    #pragma unroll
    for (int fn = 0; fn < 4; ++fn) {
        float v = yp[fn];
        v += __shfl_down(v, 32);
        if (lh == 0) red[w * 128 + fn * 32 + l31] = v;
    }
    __syncthreads();
    if (tid < 128) {
        float s2 = 0.f;
        #pragma unroll
        for (int w2 = 0; w2 < 8; ++w2) s2 += red[w2 * 128 + tid];
        Y[((size_t)nb2 * 128 + tid) * K2 + k] = s2;
    }
}

// ---------------- fallback (R1, proven 458 us, no ws) ----------------
__global__ __launch_bounds__(512, 2)
void tensor_reduction_kernel(const float* __restrict__ X,
                             const float* __restrict__ W,
                             float* __restrict__ Y)
{
    const int bid = blockIdx.x;
    const int xcd = bid & 7;
    const int rr_ = bid >> 3;
    const int kk  = xcd + 8 * (rr_ >> 4);
    const int nb  = (rr_ & 15) * 256;

    const int tid = threadIdx.x;
    const int wv  = tid >> 6;
    const int ln  = tid & 63;
    const int lg  = ln >> 4;
    const int lr  = ln & 15;

    __shared__ __align__(16) bf16_t Xs[256 * 64];
    __shared__ __align__(16) bf16_t Ws[2][64 * 64];

    bf16x8 afrag[2][16];
    {
        const int srow = tid >> 4;
        const int sj4  = (tid & 15) * 4;
        #pragma unroll
        for (int c = 0; c < 8; ++c) {
            #pragma unroll
            for (int p = 0; p < 8; ++p) {
                const int row = p * 32 + srow;
                float4 v = *reinterpret_cast<const float4*>(
                    X + (size_t)(nb + row) * D1 + c * 64 + sj4);
                bf16x4 h = { (bf16_t)v.x, (bf16_t)v.y, (bf16_t)v.z, (bf16_t)v.w };
                const int byte = row * 128 + ((sj4 * 2) ^ ((row & 7) << 4));
                *reinterpret_cast<bf16x4*>((char*)Xs + byte) = h;
            }
            __syncthreads();
            #pragma unroll
            for (int m = 0; m < 2; ++m) {
                #pragma unroll
                for (int ks = 0; ks < 2; ++ks) {
                    const int row  = wv * 32 + m * 16 + lr;
                    const int byte = row * 128 + ((ks * 64 + lg * 16) ^ ((row & 7) << 4));
                    afrag[m][2 * c + ks] =
                        *reinterpret_cast<const bf16x8*>((const char*)Xs + byte);
                }
            }
            __syncthreads();
        }
    }

    const float* Wk  = W + (size_t)kk * D1 * D1;
    const int irow = tid >> 3;
    const int j8   = (tid & 7) * 8;

    float ypart[2][4] = {{0.f,0.f,0.f,0.f},{0.f,0.f,0.f,0.f}};

    {
        const float* src = Wk + (size_t)irow * D1 + j8;
        float4 u0 = *reinterpret_cast<const float4*>(src);
        float4 u1 = *reinterpret_cast<const float4*>(src + 4);
        bf16x8 h = { (bf16_t)u0.x,(bf16_t)u0.y,(bf16_t)u0.z,(bf16_t)u0.w,
                     (bf16_t)u1.x,(bf16_t)u1.y,(bf16_t)u1.z,(bf16_t)u1.w };
        const int byte = irow * 128 + ((j8 * 2) ^ ((irow & 7) << 4));
        *reinterpret_cast<bf16x8*>((char*)Ws[0] + byte) = h;
    }
    __syncthreads();

    for (int it = 0; it < 8; ++it) {
        f32x4 acc[2][4] = {};
        #pragma unroll
        for (int jcc = 0; jcc < 8; ++jcc) {
            const int tI  = it * 8 + jcc;
            const int cur = tI & 1;
            float4 u0, u1;
            const bool pf = (tI < 63);
            if (pf) {
                const int nit = (tI + 1) >> 3, njc = (tI + 1) & 7;
                const float* src = Wk + (size_t)(nit * 64 + irow) * D1 + njc * 64 + j8;
                u0 = *reinterpret_cast<const float4*>(src);
                u1 = *reinterpret_cast<const float4*>(src + 4);
            }
            #pragma unroll
            for (int ks = 0; ks < 2; ++ks) {
                bf16x8 bfr[4];
                #pragma unroll
                for (int f = 0; f < 4; ++f) {
                    const int ir   = f * 16 + lr;
                    const int byte = ir * 128 + ((ks * 64 + lg * 16) ^ ((ir & 7) << 4));
                    bfr[f] = *reinterpret_cast<const bf16x8*>((const char*)Ws[cur] + byte);
                }
                #pragma unroll
                for (int m = 0; m < 2; ++m)
                    #pragma unroll
                    for (int f = 0; f < 4; ++f)
                        acc[m][f] = __builtin_amdgcn_mfma_f32_16x16x32_bf16(
                            afrag[m][2 * jcc + ks], bfr[f], acc[m][f], 0, 0, 0);
            }
            if (pf) {
                bf16x8 h = { (bf16_t)u0.x,(bf16_t)u0.y,(bf16_t)u0.z,(bf16_t)u0.w,
                             (bf16_t)u1.x,(bf16_t)u1.y,(bf16_t)u1.z,(bf16_t)u1.w };
                const int byte = irow * 128 + ((j8 * 2) ^ ((irow & 7) << 4));
                *reinterpret_cast<bf16x8*>((char*)Ws[cur ^ 1] + byte) = h;
            }
            __syncthreads();
        }
        #pragma unroll
        for (int m = 0; m < 2; ++m) {
            #pragma unroll
            for (int f = 0; f < 4; ++f) {
                const int col = it * 64 + f * 16 + lr;
                #pragma unroll
                for (int q = 0; q < 4; ++q) {
                    const int grow = nb + wv * 32 + m * 16 + lg * 4 + q;
                    ypart[m][q] += acc[m][f][q] * X[(size_t)grow * D1 + col];
                }
            }
        }
    }

    #pragma unroll
    for (int m = 0; m < 2; ++m) {
        #pragma unroll
        for (int q = 0; q < 4; ++q) {
            float v = ypart[m][q];
            v += __shfl_xor(v, 1, 64);
            v += __shfl_xor(v, 2, 64);
            v += __shfl_xor(v, 4, 64);
            v += __shfl_xor(v, 8, 64);
            if (lr == 0) {
                const int grow = nb + wv * 32 + m * 16 + lg * 4 + q;
                Y[(size_t)grow * K2 + kk] = v;
            }
        }
    }
}

extern "C" void kernel_launch(void* const* d_in, const int* in_sizes, int n_in,
                              void* d_out, int out_size, void* d_ws, size_t ws_size,
                              hipStream_t stream)
{
    const float* X = (const float*)d_in[0];   // [4096, 512] fp32
    const float* W = (const float*)d_in[1];   // [128, 512, 512] fp32
    float* Y = (float*)d_out;                 // [4096, 128] fp32

    if (d_ws != nullptr && ws_size >= WS_NEED) {
        bf16_t* Wbf = (bf16_t*)((char*)d_ws + WBF_OFF);
        bf16_t* Xbf = (bf16_t*)((char*)d_ws + XBF_OFF);
        prep_w<<<2048, 256, 0, stream>>>(W, Wbf);
        prep_x<<<128, 256, 0, stream>>>(X, Xbf);
        (void)hipFuncSetAttribute((const void*)tr_main,
                                  hipFuncAttributeMaxDynamicSharedMemorySize, 135168);
        tr_main<<<4096, 512, 135168, stream>>>(Wbf, Xbf, Y);
    } else {
        tensor_reduction_kernel<<<2048, 512, 0, stream>>>(X, W, Y);
    }
}